// Round 3
// baseline (853.495 us; speedup 1.0000x reference)
//
#include <hip/hip_runtime.h>
#include <math.h>

// ---------------------------------------------------------------------------
// SimGNN forward on MI355X — combined-graph, fused pipeline.
// M = 2N nodes (graph-2 ids offset +N), one CSR build, per-edge (src, dinv[src])
// packed as int2 so fill does ONE scattered 8B store and agg does ONE coalesced
// 8B edge load.
//   k1: x1 = relu((A x0)@W1 + b1)                 [fused agg64 + gemm64]
//   k2: h3 = relu((A x1)@W2 + b2) @ W3            [fused agg64 + gemm64 + gemm64_32]
//   k3: a3 = A h3 + b3, msum += colsum(a3)        [fused agg32 + colsum]
//   ctx = tanh(msum/N @ W_att); pooled = a3^T sigmoid(a3 ctx); NTN -> 16 floats
// A applied as out[v] = dinv[v]*( x[v]*dinv[v] + sum_{(u->v)} x[u]*dinv[u] ).
// ---------------------------------------------------------------------------

__global__ void count2_kernel(const int* __restrict__ ei1, const int* __restrict__ ei2,
                              int E, int N, int* __restrict__ counts) {
    int i = blockIdx.x * blockDim.x + threadIdx.x;
    if (i < E)          atomicAdd(&counts[ei1[E + i]], 1);
    else if (i < 2 * E) atomicAdd(&counts[ei2[E + (i - E)] + N], 1);
}

// ---- 3-phase scan over counts[M] -> row_ptr[M+1], dinv[M] ----
__global__ void scanA_kernel(const int* __restrict__ counts, int* __restrict__ bsum, int M) {
    __shared__ int sh[256];
    int t = threadIdx.x;
    int base = blockIdx.x * 1024 + t * 4;
    int s = 0;
    #pragma unroll
    for (int k = 0; k < 4; ++k) { int idx = base + k; if (idx < M) s += counts[idx]; }
    sh[t] = s;
    __syncthreads();
    for (int off = 128; off; off >>= 1) {
        if (t < off) sh[t] += sh[t + off];
        __syncthreads();
    }
    if (t == 0) bsum[blockIdx.x] = sh[0];
}

__global__ void scanB_kernel(int* __restrict__ bsum, int P, int* __restrict__ row_ptr, int M) {
    __shared__ int sh[256];
    int t = threadIdx.x;
    sh[t] = (t < P) ? bsum[t] : 0;
    __syncthreads();
    for (int off = 1; off < 256; off <<= 1) {
        int v = (t >= off) ? sh[t - off] : 0;
        __syncthreads();
        sh[t] += v;
        __syncthreads();
    }
    if (t < P) bsum[t] = (t == 0) ? 0 : sh[t - 1];
    if (t == 255) row_ptr[M] = sh[255];
}

__global__ void scanC_kernel(const int* __restrict__ counts, const int* __restrict__ bsum,
                             int* __restrict__ row_ptr, float* __restrict__ dinv, int M) {
    __shared__ int sh[256];
    int t = threadIdx.x;
    int base = blockIdx.x * 1024 + t * 4;
    int c[4];
    int s = 0;
    #pragma unroll
    for (int k = 0; k < 4; ++k) { int idx = base + k; c[k] = (idx < M) ? counts[idx] : 0; s += c[k]; }
    sh[t] = s;
    __syncthreads();
    for (int off = 1; off < 256; off <<= 1) {
        int v = (t >= off) ? sh[t - off] : 0;
        __syncthreads();
        sh[t] += v;
        __syncthreads();
    }
    int run = bsum[blockIdx.x] + ((t == 0) ? 0 : sh[t - 1]);
    #pragma unroll
    for (int k = 0; k < 4; ++k) {
        int idx = base + k;
        if (idx < M) {
            row_ptr[idx] = run;
            dinv[idx] = rsqrtf((float)(c[k] + 1));
            run += c[k];
        }
    }
}

// counts doubles as the per-row cursor; one 8B scattered store per edge.
__global__ void fill2_kernel(const int* __restrict__ ei1, const int* __restrict__ ei2,
                             int E, int N, const int* __restrict__ row_ptr,
                             int* __restrict__ counts, const float* __restrict__ dinv,
                             int2* __restrict__ edges) {
    int i = blockIdx.x * blockDim.x + threadIdx.x;
    int src, dst;
    if (i < E)          { src = ei1[i];             dst = ei1[E + i]; }
    else if (i < 2 * E) { src = ei2[i - E] + N;     dst = ei2[E + (i - E)] + N; }
    else return;
    int p = atomicSub(&counts[dst], 1) - 1;
    edges[row_ptr[dst] + p] = make_int2(src, __float_as_int(dinv[src]));
}

// k1: wave-per-node grid-stride; agg64 then 64x64 GEMM (+bias, relu).
__global__ void agg_gemm64_kernel(const float* __restrict__ x1, const float* __restrict__ x2,
                                  float* __restrict__ out, const int* __restrict__ row_ptr,
                                  const int2* __restrict__ edges, const float* __restrict__ dinv,
                                  const float* __restrict__ W, const float* __restrict__ b,
                                  int N, int M, int num_waves) {
    __shared__ float Ws[64 * 64];
    for (int i = threadIdx.x; i < 64 * 64; i += blockDim.x) Ws[i] = W[i];
    __syncthreads();
    int lane = threadIdx.x & 63;
    int wid = (blockIdx.x * blockDim.x + threadIdx.x) >> 6;
    float bj = b[lane];
    for (int v = wid; v < M; v += num_waves) {
        const float* xb = (v < N) ? x1 : (x2 - (size_t)N * 64);
        float dv = dinv[v];
        float acc = xb[(size_t)v * 64 + lane] * dv;   // self-loop (final *dv -> dv^2)
        int s = row_ptr[v], e = row_ptr[v + 1];
        int i = s;
        for (; i + 4 <= e; i += 4) {
            int2 e0 = edges[i], e1 = edges[i + 1], e2 = edges[i + 2], e3 = edges[i + 3];
            float a0 = xb[(size_t)e0.x * 64 + lane];
            float a1 = xb[(size_t)e1.x * 64 + lane];
            float a2 = xb[(size_t)e2.x * 64 + lane];
            float a3 = xb[(size_t)e3.x * 64 + lane];
            acc += a0 * __int_as_float(e0.y) + a1 * __int_as_float(e1.y)
                 + a2 * __int_as_float(e2.y) + a3 * __int_as_float(e3.y);
        }
        for (; i < e; ++i) {
            int2 ed = edges[i];
            acc += xb[(size_t)ed.x * 64 + lane] * __int_as_float(ed.y);
        }
        acc *= dv;
        float o = bj;
        #pragma unroll
        for (int k = 0; k < 64; ++k) o += __shfl(acc, k) * Ws[k * 64 + lane];
        o = fmaxf(o, 0.f);
        out[(size_t)v * 64 + lane] = o;
    }
}

// k2: agg64 + gemm64 (relu) + gemm 64->32; writes h3 [M,32] only.
__global__ void agg_gemm64_gemm32_kernel(const float* __restrict__ x,
                                         float* __restrict__ out, const int* __restrict__ row_ptr,
                                         const int2* __restrict__ edges, const float* __restrict__ dinv,
                                         const float* __restrict__ W2, const float* __restrict__ b2,
                                         const float* __restrict__ W3, int M, int num_waves) {
    __shared__ float Ws2[64 * 64];
    __shared__ float Ws3[64 * 32];
    for (int i = threadIdx.x; i < 64 * 64; i += blockDim.x) Ws2[i] = W2[i];
    for (int i = threadIdx.x; i < 64 * 32; i += blockDim.x) Ws3[i] = W3[i];
    __syncthreads();
    int lane = threadIdx.x & 63;
    int j32 = lane & 31;
    int wid = (blockIdx.x * blockDim.x + threadIdx.x) >> 6;
    float bj = b2[lane];
    for (int v = wid; v < M; v += num_waves) {
        float dv = dinv[v];
        float acc = x[(size_t)v * 64 + lane] * dv;
        int s = row_ptr[v], e = row_ptr[v + 1];
        int i = s;
        for (; i + 4 <= e; i += 4) {
            int2 e0 = edges[i], e1 = edges[i + 1], e2 = edges[i + 2], e3 = edges[i + 3];
            float a0 = x[(size_t)e0.x * 64 + lane];
            float a1 = x[(size_t)e1.x * 64 + lane];
            float a2 = x[(size_t)e2.x * 64 + lane];
            float a3 = x[(size_t)e3.x * 64 + lane];
            acc += a0 * __int_as_float(e0.y) + a1 * __int_as_float(e1.y)
                 + a2 * __int_as_float(e2.y) + a3 * __int_as_float(e3.y);
        }
        for (; i < e; ++i) {
            int2 ed = edges[i];
            acc += x[(size_t)ed.x * 64 + lane] * __int_as_float(ed.y);
        }
        acc *= dv;
        float x2v = bj;
        #pragma unroll
        for (int k = 0; k < 64; ++k) x2v += __shfl(acc, k) * Ws2[k * 64 + lane];
        x2v = fmaxf(x2v, 0.f);
        float h = 0.f;
        #pragma unroll
        for (int k = 0; k < 64; ++k) h += __shfl(x2v, k) * Ws3[k * 32 + j32];
        if (lane < 32) out[(size_t)v * 32 + lane] = h;
    }
}

// k3: agg32 + bias; fused per-graph column sums into msum[g*32+j].
// Grid split: blocks [0, halfgrid) -> graph 0, [halfgrid, 2*halfgrid) -> graph 1.
__global__ void agg32_colsum_kernel(const float* __restrict__ h, float* __restrict__ out,
                                    const int* __restrict__ row_ptr, const int2* __restrict__ edges,
                                    const float* __restrict__ dinv, const float* __restrict__ b,
                                    float* __restrict__ msum, int N, int halfgrid) {
    int g = (blockIdx.x >= halfgrid) ? 1 : 0;
    int bid = blockIdx.x - g * halfgrid;
    int t = threadIdx.x;
    int lane = t & 31;
    int hw = (bid * blockDim.x + t) >> 5;
    int nhw = (halfgrid * blockDim.x) >> 5;
    float bl = b[lane];
    float csum = 0.f;
    int base = g * N;
    for (int vv = hw; vv < N; vv += nhw) {
        int v = base + vv;
        float dv = dinv[v];
        float acc = h[(size_t)v * 32 + lane] * dv;
        int s = row_ptr[v], e = row_ptr[v + 1];
        int i = s;
        for (; i + 4 <= e; i += 4) {
            int2 e0 = edges[i], e1 = edges[i + 1], e2 = edges[i + 2], e3 = edges[i + 3];
            acc += h[(size_t)e0.x * 32 + lane] * __int_as_float(e0.y)
                 + h[(size_t)e1.x * 32 + lane] * __int_as_float(e1.y)
                 + h[(size_t)e2.x * 32 + lane] * __int_as_float(e2.y)
                 + h[(size_t)e3.x * 32 + lane] * __int_as_float(e3.y);
        }
        for (; i < e; ++i) {
            int2 ed = edges[i];
            acc += h[(size_t)ed.x * 32 + lane] * __int_as_float(ed.y);
        }
        float o = acc * dv + bl;
        out[(size_t)v * 32 + lane] = o;
        csum += o;
    }
    __shared__ float sp[256];
    sp[t] = csum;
    __syncthreads();
    if (t < 32) {
        float s = 0.f;
        for (int w = 0; w < 8; ++w) s += sp[w * 32 + t];
        atomicAdd(&msum[g * 32 + t], s);
    }
}

// ctx[g*32+j] = tanh( sum_i (msum[g*32+i]/N) * W_att[i][j] ); one 64-thread block.
__global__ void ctx2_kernel(const float* __restrict__ msum, const float* __restrict__ W_att,
                            float* __restrict__ ctx, int N) {
    int t = threadIdx.x;
    if (t >= 64) return;
    int g = t >> 5, j = t & 31;
    float invN = 1.f / (float)N;
    float acc = 0.f;
    for (int i = 0; i < 32; ++i) acc += (msum[g * 32 + i] * invN) * W_att[i * 32 + j];
    ctx[g * 32 + j] = tanhf(acc);
}

// pooled[g*32+j] = sum_n sigmoid(a3[n].ctx_g) * a3[n][j]
__global__ void pool2_kernel(const float* __restrict__ a3, const float* __restrict__ ctx,
                             float* __restrict__ pooled, int N, int halfgrid) {
    int g = (blockIdx.x >= halfgrid) ? 1 : 0;
    int bid = blockIdx.x - g * halfgrid;
    int t = threadIdx.x;
    int j = t & 31;
    int hw = (bid * blockDim.x + t) >> 5;
    int nhw = (halfgrid * blockDim.x) >> 5;
    const float* base = a3 + (size_t)g * N * 32;
    float cj = ctx[g * 32 + j];
    float local = 0.f;
    for (int n = hw; n < N; n += nhw) {
        float v = base[(size_t)n * 32 + j];
        float d = v * cj;
        #pragma unroll
        for (int off = 16; off; off >>= 1) d += __shfl_xor(d, off);  // stays within 32-lane half
        float s = 1.f / (1.f + __expf(-d));
        local += s * v;
    }
    __shared__ float sp[256];
    sp[t] = local;
    __syncthreads();
    if (t < 32) {
        float s = 0.f;
        for (int w = 0; w < 8; ++w) s += sp[w * 32 + t];
        atomicAdd(&pooled[g * 32 + t], s);
    }
}

// NTN: out[k] = relu( sum_ij e1[i] W_tn[i,j,k] e2[j] + W_block[k].[e1;e2] + b_tn[k] )
__global__ void ntn_kernel(const float* __restrict__ p1, const float* __restrict__ p2,
                           const float* __restrict__ W_tn, const float* __restrict__ W_block,
                           const float* __restrict__ b_tn, float* __restrict__ out) {
    int k = threadIdx.x;
    if (k >= 16) return;
    float sc = 0.f;
    for (int i = 0; i < 32; ++i) {
        float e1 = p1[i];
        for (int j = 0; j < 32; ++j) sc += e1 * W_tn[i * 512 + j * 16 + k] * p2[j];
    }
    float bl = 0.f;
    for (int j = 0; j < 32; ++j)
        bl += W_block[k * 64 + j] * p1[j] + W_block[k * 64 + 32 + j] * p2[j];
    float v = sc + bl + b_tn[k];
    out[k] = v > 0.f ? v : 0.f;
}

extern "C" void kernel_launch(void* const* d_in, const int* in_sizes, int n_in,
                              void* d_out, int out_size, void* d_ws, size_t ws_size,
                              hipStream_t stream) {
    const float* f1     = (const float*)d_in[0];
    const int*   ei1    = (const int*)  d_in[1];
    const float* f2     = (const float*)d_in[2];
    const int*   ei2    = (const int*)  d_in[3];
    const float* W1     = (const float*)d_in[4];
    const float* b1     = (const float*)d_in[5];
    const float* W2     = (const float*)d_in[6];
    const float* b2     = (const float*)d_in[7];
    const float* W3     = (const float*)d_in[8];
    const float* b3     = (const float*)d_in[9];
    const float* W_att  = (const float*)d_in[10];
    const float* W_tn   = (const float*)d_in[11];
    const float* W_blk  = (const float*)d_in[12];
    const float* b_tn   = (const float*)d_in[13];

    int N = in_sizes[0] / 64;
    int E = in_sizes[1] / 2;
    int M = 2 * N;
    int E2 = 2 * E;

    char* ws = (char*)d_ws;
    size_t off = 0;
    auto alloc = [&](size_t bytes) -> void* {
        void* p = ws + off;
        off += (bytes + 511) & ~(size_t)511;
        return p;
    };
    float* bufA    = (float*)alloc((size_t)M * 64 * sizeof(float));   // x1 then a3
    float* bufB    = (float*)alloc((size_t)M * 32 * sizeof(float));   // h3
    int2*  edges   = (int2*) alloc((size_t)E2 * sizeof(int2));
    int*   row_ptr = (int*)  alloc((size_t)(M + 1) * sizeof(int));
    int*   counts  = (int*)  alloc((size_t)M * sizeof(int));
    float* dinv    = (float*)alloc((size_t)M * sizeof(float));
    int*   bsum    = (int*)  alloc(256 * sizeof(int));
    float* smalls  = (float*)alloc(256 * sizeof(float));
    float* msum   = smalls;        // [64]
    float* pooled = smalls + 64;   // [64]
    float* ctx    = smalls + 128;  // [64]

    hipMemsetAsync(smalls, 0, 256 * sizeof(float), stream);
    hipMemsetAsync(counts, 0, (size_t)M * sizeof(int), stream);

    int eb = (E2 + 255) / 256;
    int P  = (M + 1023) / 1024;

    // CSR build
    count2_kernel<<<eb, 256, 0, stream>>>(ei1, ei2, E, N, counts);
    scanA_kernel<<<P, 256, 0, stream>>>(counts, bsum, M);
    scanB_kernel<<<1, 256, 0, stream>>>(bsum, P, row_ptr, M);
    scanC_kernel<<<P, 256, 0, stream>>>(counts, bsum, row_ptr, dinv, M);
    fill2_kernel<<<eb, 256, 0, stream>>>(ei1, ei2, E, N, row_ptr, counts, dinv, edges);

    // Fused GCN stack
    const int GBLK = 2048;                 // grid-stride waves
    int num_waves = GBLK * (256 / 64);
    agg_gemm64_kernel<<<GBLK, 256, 0, stream>>>(f1, f2, bufA, row_ptr, edges, dinv, W1, b1, N, M, num_waves);
    agg_gemm64_gemm32_kernel<<<GBLK, 256, 0, stream>>>(bufA, bufB, row_ptr, edges, dinv, W2, b2, W3, M, num_waves);

    // a3 written into bufA (reuse), colsum fused
    const int HG = 512;
    agg32_colsum_kernel<<<2 * HG, 256, 0, stream>>>(bufB, bufA, row_ptr, edges, dinv, b3, msum, N, HG);

    ctx2_kernel<<<1, 64, 0, stream>>>(msum, W_att, ctx, N);
    pool2_kernel<<<2 * 256, 256, 0, stream>>>(bufA, ctx, pooled, N, 256);
    ntn_kernel<<<1, 64, 0, stream>>>(pooled, pooled + 32, W_tn, W_blk, b_tn, (float*)d_out);
}